// Round 7
// baseline (484.145 us; speedup 1.0000x reference)
//
#include <hip/hip_runtime.h>

typedef __attribute__((ext_vector_type(4))) float f32x4;
typedef __attribute__((ext_vector_type(8))) short s16x8;
typedef __attribute__((ext_vector_type(4))) unsigned short u16x4;

#define DEV __device__ __forceinline__

DEV unsigned short f2bf(float f) {
  unsigned int u = __float_as_uint(f);
  return (unsigned short)((u + 0x7FFFu + ((u >> 16) & 1u)) >> 16);
}

DEV float exp2_asm(float x) {        // v_exp_f32: D = 2^S0
  float r; asm("v_exp_f32 %0, %1" : "=v"(r) : "v"(x)); return r;
}
DEV float rcp_asm(float x) {
  float r; asm("v_rcp_f32 %0, %1" : "=v"(r) : "v"(x)); return r;
}

DEV void gload_lds16(const void* g, void* l) {
  __builtin_amdgcn_global_load_lds(
      (const __attribute__((address_space(1))) unsigned int*)g,
      (__attribute__((address_space(3))) unsigned int*)l, 16, 0, 0);
}

// ---------------- LayerNorm: fp32 in -> bf16 out (rows of 1024) ----------------
__global__ __launch_bounds__(256) void ln_kernel(
    const float* __restrict__ x, const float* __restrict__ gam,
    const float* __restrict__ bet, unsigned short* __restrict__ o)
{
  const int row = blockIdx.x;
  const int tid = threadIdx.x;
  f32x4 v = *(const f32x4*)(x + (size_t)row * 1024 + tid * 4);
  float s = v[0] + v[1] + v[2] + v[3];
  float s2 = v[0]*v[0] + v[1]*v[1] + v[2]*v[2] + v[3]*v[3];
  #pragma unroll
  for (int m = 1; m < 64; m <<= 1) { s += __shfl_xor(s, m); s2 += __shfl_xor(s2, m); }
  __shared__ float ps[4], ps2[4];
  const int wid = tid >> 6, lane = tid & 63;
  if (lane == 0) { ps[wid] = s; ps2[wid] = s2; }
  __syncthreads();
  s = ps[0] + ps[1] + ps[2] + ps[3];
  s2 = ps2[0] + ps2[1] + ps2[2] + ps2[3];
  const float mu = s * (1.0f / 1024.0f);
  const float rstd = rsqrtf(s2 * (1.0f / 1024.0f) - mu * mu + 1e-5f);
  f32x4 g4 = *(const f32x4*)(gam + tid * 4);
  f32x4 b4 = *(const f32x4*)(bet + tid * 4);
  u16x4 ov;
  #pragma unroll
  for (int j = 0; j < 4; j++) ov[j] = f2bf((v[j] - mu) * rstd * g4[j] + b4[j]);
  *(u16x4*)(o + (size_t)row * 1024 + tid * 4) = ov;
}

// -------- transpose+convert: W[K][N] f32 -> WT[N][K] bf16 (64x64 LDS tiles) --------
__global__ __launch_bounds__(256) void transpose_kernel(
    const float* __restrict__ W, unsigned short* __restrict__ WT, int K, int N)
{
  __shared__ float tile[64][65];
  const int n0 = blockIdx.x * 64, k0 = blockIdx.y * 64;
  const int c = threadIdx.x & 63, r0 = threadIdx.x >> 6;
  #pragma unroll
  for (int r = r0; r < 64; r += 4)
    tile[r][c] = W[(size_t)(k0 + r) * N + n0 + c];
  __syncthreads();
  #pragma unroll
  for (int r = r0; r < 64; r += 4)
    WT[(size_t)(n0 + r) * K + k0 + c] = f2bf(tile[c][r]);
}

// --- 128x256 GEMM, BK=64, XOR-swizzled LDS, 3-slot ring, ONE barrier/K-tile ---
// (unchanged from R6)
template <int MODE>
__global__ __launch_bounds__(512) void gemm8_kernel(
    const unsigned short* __restrict__ A, const unsigned short* __restrict__ WT,
    const float* __restrict__ bias, const float* resid, void* outp,
    int M, int N, int K)
{
  __shared__ unsigned short lds[3 * 24576];   // slot: A 128x64 (16KB) + B 256x64 (32KB)
  const int tid = threadIdx.x;
  const int lane = tid & 63, wid = tid >> 6;
  const int l15 = lane & 15, l4 = lane >> 4;
  const int wm = wid >> 2, wn = wid & 3;
  const int tiles_n = N >> 8;
  const int cpx = gridDim.x >> 3;
  const int id = (blockIdx.x & 7) * cpx + (blockIdx.x >> 3);
  const int bm = id / tiles_n, bn = id % tiles_n;
  const int NT = K >> 6;

  const int srow = tid >> 3;
  const int scol = ((tid & 7) ^ (srow & 7)) * 8;
  const unsigned short* Asrc = A  + (size_t)(bm * 128 + srow) * K + scol;
  const unsigned short* Bsrc = WT + (size_t)(bn * 256 + srow) * K + scol;
  const size_t j64 = (size_t)64 * K;
  const int dwave = wid * 1024;

#define STAGE(t_, ss_) do { \
    char* base_ = (char*)lds + (ss_) * 49152 + dwave; \
    const unsigned short* sA_ = Asrc + (size_t)(t_) * 64; \
    const unsigned short* sB_ = Bsrc + (size_t)(t_) * 64; \
    gload_lds16(sA_,            base_); \
    gload_lds16(sA_ + j64,      base_ + 8192); \
    gload_lds16(sB_,            base_ + 16384); \
    gload_lds16(sB_ + j64,      base_ + 16384 + 8192); \
    gload_lds16(sB_ + 2 * j64,  base_ + 16384 + 16384); \
    gload_lds16(sB_ + 3 * j64,  base_ + 16384 + 24576); \
  } while (0)

  f32x4 acc[4][4] = {};

  const int arow0 = wm * 64 + l15;
  const int brow0 = wn * 64 + l15;
  const int cswz = l15 & 7;

  STAGE(0, 0);
  STAGE(1, 1);
  asm volatile("s_waitcnt vmcnt(6)" ::: "memory");
  __builtin_amdgcn_s_barrier();

  int cs = 0, ss = 2;
  for (int t = 0; t < NT; ++t) {
    const unsigned short* sa = lds + cs * 24576;
    const unsigned short* sb = sa + 8192;
    s16x8 af[4][2], bf[4][2];
    #pragma unroll
    for (int mf = 0; mf < 4; ++mf)
      #pragma unroll
      for (int ks = 0; ks < 2; ++ks)
        af[mf][ks] = *(const s16x8*)&sa[(arow0 + mf * 16) * 64 + (((ks * 4 + l4) ^ cswz) * 8)];
    #pragma unroll
    for (int nf = 0; nf < 4; ++nf)
      #pragma unroll
      for (int ks = 0; ks < 2; ++ks)
        bf[nf][ks] = *(const s16x8*)&sb[(brow0 + nf * 16) * 64 + (((ks * 4 + l4) ^ cswz) * 8)];
    if (t + 2 < NT) STAGE(t + 2, ss);
    __builtin_amdgcn_s_setprio(1);
    #pragma unroll
    for (int mf = 0; mf < 4; ++mf)
      #pragma unroll
      for (int nf = 0; nf < 4; ++nf)
        #pragma unroll
        for (int ks = 0; ks < 2; ++ks)
          acc[mf][nf] = __builtin_amdgcn_mfma_f32_16x16x32_bf16(
              af[mf][ks], bf[nf][ks], acc[mf][nf], 0, 0, 0);
    __builtin_amdgcn_s_setprio(0);
    if (t + 2 < NT)      { asm volatile("s_waitcnt vmcnt(6)" ::: "memory"); }
    else if (t + 1 < NT) { asm volatile("s_waitcnt vmcnt(0)" ::: "memory"); }
    __builtin_amdgcn_s_barrier();
    cs = (cs == 2) ? 0 : cs + 1;
    ss = (ss == 2) ? 0 : ss + 1;
  }
#undef STAGE

  #pragma unroll
  for (int nf = 0; nf < 4; nf++) {
    const int col = bn * 256 + wn * 64 + nf * 16 + l15;
    const float bv = bias[col];
    #pragma unroll
    for (int mf = 0; mf < 4; mf++) {
      #pragma unroll
      for (int r = 0; r < 4; r++) {
        const int row = bm * 128 + wm * 64 + mf * 16 + l4 * 4 + r;
        const size_t off = (size_t)row * N + col;
        float v = acc[mf][nf][r] + bv;
        if (MODE == 1) {
          ((float*)outp)[off] = v + resid[off];
        } else if (MODE == 2) {
          const float u = v + 0.044715f * v * v * v;
          const float e = exp2_asm(-2.3022010f * u);
          ((unsigned short*)outp)[off] = f2bf(v * rcp_asm(1.0f + e));
        } else {
          ((unsigned short*)outp)[off] = f2bf(v);
        }
      }
    }
  }
}

// ---------------- causal flash attention ----------------
// R7: merged qA/qB tile pass (each K/V fragment read from LDS ONCE, two MFMAs)
// + fixed Vt swizzle f(d) = ((d>>2)&3)|((d&1)<<2) so vf reads hit all 8 bank
// groups (s/8 = (ks*4+l4)^f varies in all 3 bits across lanes). Async K/V
// prefetch with raw barriers + counted vmcnt, log2-softmax + defer-max kept.
struct AttnState {
  f32x4 o[4];
  float m, l;
};

DEV int vt_f(int d) { return ((d >> 2) & 3) | ((d & 1) << 2); }

DEV void attn_softmax(f32x4* sa, AttnState& st, unsigned short* Pw,
                      int kv0, int qg, int l15, int l4, bool need_mask)
{
  float mx = -3.0e38f;
  const int thr = qg - kv0 - l4 * 4;
  #pragma unroll
  for (int cb = 0; cb < 4; cb++)
    #pragma unroll
    for (int r = 0; r < 4; r++) {
      float sv = sa[cb][r] * 0.18033688f;        // 0.125 * log2(e)
      if (need_mask && (cb * 16 + r > thr)) sv = -3.0e38f;
      sa[cb][r] = sv;
      mx = fmaxf(mx, sv);
    }
  mx = fmaxf(mx, __shfl_xor(mx, 16));
  mx = fmaxf(mx, __shfl_xor(mx, 32));
  const bool skip = __all(mx <= st.m + 11.5f);   // defer-max
  const float mnew = skip ? st.m : fmaxf(st.m, mx);
  float rsum = 0.f;
  #pragma unroll
  for (int cb = 0; cb < 4; cb++) {
    u16x4 pw;
    #pragma unroll
    for (int r = 0; r < 4; r++) {
      const float p = exp2_asm(sa[cb][r] - mnew);
      rsum += p;
      pw[r] = f2bf(p);
    }
    *(u16x4*)&Pw[l15 * 64 + ((cb * 16 + l4 * 4) ^ ((l15 & 7) << 3))] = pw;
  }
  rsum += __shfl_xor(rsum, 16);
  rsum += __shfl_xor(rsum, 32);
  if (skip) {
    st.l += rsum;
  } else {
    const float alpha = exp2_asm(st.m - mnew);
    st.l = st.l * alpha + rsum;
    st.m = mnew;
    #pragma unroll
    for (int r = 0; r < 4; r++) {
      const float ar = __shfl(alpha, l4 * 4 + r);
      #pragma unroll
      for (int cb = 0; cb < 4; cb++) st.o[cb][r] *= ar;
    }
  }
}

DEV void attn_tile2(const s16x8* qfA, const s16x8* qfB,
                    const unsigned short* Ks, const unsigned short* Vt,
                    unsigned short* PwA, unsigned short* PwB,
                    AttnState& sA, AttnState& sB, int kv0,
                    int qgA, int qgB, int l15, int l4,
                    bool maskA, bool maskB, bool doA)
{
  f32x4 saA[4], saB[4];
  #pragma unroll
  for (int cb = 0; cb < 4; cb++) {
    saA[cb] = (f32x4){0.f, 0.f, 0.f, 0.f};
    saB[cb] = (f32x4){0.f, 0.f, 0.f, 0.f};
  }
  __builtin_amdgcn_s_setprio(1);
  #pragma unroll
  for (int ks = 0; ks < 2; ++ks) {
    #pragma unroll
    for (int cb = 0; cb < 4; cb++) {
      const int kvr = cb * 16 + l15;
      s16x8 bk = *(const s16x8*)&Ks[kvr * 64 + ((ks * 32 + l4 * 8) ^ ((kvr & 7) << 3))];
      if (doA) saA[cb] = __builtin_amdgcn_mfma_f32_16x16x32_bf16(bk, qfA[ks], saA[cb], 0, 0, 0);
      saB[cb] = __builtin_amdgcn_mfma_f32_16x16x32_bf16(bk, qfB[ks], saB[cb], 0, 0, 0);
    }
  }
  __builtin_amdgcn_s_setprio(0);
  if (doA) attn_softmax(saA, sA, PwA, kv0, qgA, l15, l4, maskA);
  attn_softmax(saB, sB, PwB, kv0, qgB, l15, l4, maskB);
  asm volatile("s_waitcnt lgkmcnt(0)" ::: "memory");  // P writes visible to own wave
  __builtin_amdgcn_s_setprio(1);
  #pragma unroll
  for (int ks = 0; ks < 2; ++ks) {
    s16x8 paA, paB;
    if (doA) paA = *(const s16x8*)&PwA[l15 * 64 + ((ks * 32 + l4 * 8) ^ ((l15 & 7) << 3))];
    paB = *(const s16x8*)&PwB[l15 * 64 + ((ks * 32 + l4 * 8) ^ ((l15 & 7) << 3))];
    #pragma unroll
    for (int cb = 0; cb < 4; cb++) {
      const int d = cb * 16 + l15;
      s16x8 vf = *(const s16x8*)&Vt[d * 64 + ((ks * 32 + l4 * 8) ^ (vt_f(d) << 3))];
      if (doA) sA.o[cb] = __builtin_amdgcn_mfma_f32_16x16x32_bf16(paA, vf, sA.o[cb], 0, 0, 0);
      sB.o[cb] = __builtin_amdgcn_mfma_f32_16x16x32_bf16(paB, vf, sB.o[cb], 0, 0, 0);
    }
  }
  __builtin_amdgcn_s_setprio(0);
}

DEV void attn_write(unsigned short* orow, const AttnState& st, int l15, int l4) {
  const float invl = rcp_asm(st.l);
  #pragma unroll
  for (int r = 0; r < 4; r++) {
    const float ir = __shfl(invl, l4 * 4 + r);
    #pragma unroll
    for (int cb = 0; cb < 4; cb++)
      orow[(l4 * 4 + r) * 1024 + cb * 16 + l15] = f2bf(st.o[cb][r] * ir);
  }
}

__global__ __launch_bounds__(256) void attn_kernel(
    const unsigned short* __restrict__ qkv, unsigned short* __restrict__ outb)
{
  __shared__ unsigned short Ks[2][64 * 64];       // [kv][d^((kv&7)<<3)], double-buffered
  __shared__ unsigned short Vt[64 * 64];          // [d][kv^(vt_f(d)<<3)]
  __shared__ unsigned short Ps[2][4][16 * 64];    // per-q-tile, per-wave P
  const int pid = blockIdx.x;                     // 0..15
  const int qA = pid, qB = 31 - pid;
  const int bh = blockIdx.y;
  const int b = bh >> 4, h = bh & 15;
  const int tid = threadIdx.x, lane = tid & 63, wid = tid >> 6;
  const int l15 = lane & 15, l4 = lane >> 4;
  const size_t base = (size_t)b * 2048 * 3072 + (size_t)h * 64;
  const unsigned short* Qb = qkv + base;
  const unsigned short* Kb = qkv + base + 1024;
  const unsigned short* Vb = qkv + base + 2048;

  s16x8 qfA[2], qfB[2];
  {
    const unsigned short* qr = Qb + (size_t)(qA * 64 + wid * 16 + l15) * 3072 + l4 * 8;
    qfA[0] = *(const s16x8*)qr;
    qfA[1] = *(const s16x8*)(qr + 32);
    qr = Qb + (size_t)(qB * 64 + wid * 16 + l15) * 3072 + l4 * 8;
    qfB[0] = *(const s16x8*)qr;
    qfB[1] = *(const s16x8*)(qr + 32);
  }

  // prologue: V(0) reg loads FIRST, then K(0) gload_lds (vmcnt counts rely on order)
  u16x4 vv[4];
  #pragma unroll
  for (int it = 0; it < 4; ++it) {
    const int cc = tid + 256 * it;
    vv[it] = *(const u16x4*)(Vb + (size_t)(cc >> 4) * 3072 + (cc & 15) * 4);
  }
  #pragma unroll
  for (int s = 0; s < 2; ++s) {
    const int c = s * 256 + tid;
    const int kv = c >> 3;
    const int dsrc = ((c & 7) * 8) ^ ((kv & 7) << 3);
    gload_lds16(Kb + (size_t)kv * 3072 + dsrc, &Ks[0][(size_t)(c & ~63) * 8]);
  }

  AttnState sA, sB;
  #pragma unroll
  for (int cb = 0; cb < 4; cb++) {
    sA.o[cb] = (f32x4){0.f, 0.f, 0.f, 0.f};
    sB.o[cb] = (f32x4){0.f, 0.f, 0.f, 0.f};
  }
  sA.m = -1e30f; sA.l = 0.f; sB.m = -1e30f; sB.l = 0.f;
  const int qgA = qA * 64 + wid * 16 + l15;
  const int qgB = qB * 64 + wid * 16 + l15;

  for (int kvb = 0; kvb <= qB; ++kvb) {
    const int cur = kvb & 1;
    const int kv0 = kvb * 64;
    __builtin_amdgcn_s_barrier();                 // #1: prev tile fully consumed
    asm volatile("s_waitcnt vmcnt(2)" ::: "memory");   // V(kvb) regs landed; K(kvb) flying
    // publish V(kvb): reg -> swizzled Vt
    #pragma unroll
    for (int it = 0; it < 4; ++it) {
      const int cc = tid + 256 * it;
      const int vkv = cc >> 4;
      const int vd = (cc & 15) * 4;
      #pragma unroll
      for (int j = 0; j < 4; j++) {
        const int d = vd + j;
        Vt[d * 64 + (vkv ^ (vt_f(d) << 3))] = vv[it][j];
      }
    }
    if (kvb < qB) {
      // prefetch V(kvb+1) into regs (stays in flight across compute)
      #pragma unroll
      for (int it = 0; it < 4; ++it) {
        const int cc = tid + 256 * it;
        vv[it] = *(const u16x4*)(Vb + (size_t)((kvb + 1) * 64 + (cc >> 4)) * 3072 + (cc & 15) * 4);
      }
      asm volatile("s_waitcnt vmcnt(4)" ::: "memory");  // K(kvb) landed; V(kvb+1) flying
    } else {
      asm volatile("s_waitcnt vmcnt(0)" ::: "memory");
    }
    asm volatile("s_waitcnt lgkmcnt(0)" ::: "memory");  // Vt ds_writes drained
    __builtin_amdgcn_s_barrier();                 // #2: Ks[cur], Vt published
    if (kvb < qB) {
      // prefetch K(kvb+1) -> Ks[cur^1] (readers of that slot finished pre-#1)
      #pragma unroll
      for (int s = 0; s < 2; ++s) {
        const int c = s * 256 + tid;
        const int kv = c >> 3;
        const int dsrc = ((c & 7) * 8) ^ ((kv & 7) << 3);
        gload_lds16(Kb + (size_t)((kvb + 1) * 64 + kv) * 3072 + dsrc,
                    &Ks[cur ^ 1][(size_t)(c & ~63) * 8]);
      }
    }
    attn_tile2(qfA, qfB, Ks[cur], Vt, Ps[0][wid], Ps[1][wid], sA, sB,
               kv0, qgA, qgB, l15, l4,
               kv0 + 63 > qA * 64 + wid * 16,
               kv0 + 63 > qB * 64 + wid * 16,
               kvb <= qA);
  }
  attn_write(outb + ((size_t)b * 2048 + qA * 64 + wid * 16) * 1024 + h * 64, sA, l15, l4);
  attn_write(outb + ((size_t)b * 2048 + qB * 64 + wid * 16) * 1024 + h * 64, sB, l15, l4);
}

// ---------------- host ----------------
extern "C" void kernel_launch(void* const* d_in, const int* in_sizes, int n_in,
                              void* d_out, int out_size, void* d_ws, size_t ws_size,
                              hipStream_t stream) {
  const float* x      = (const float*)d_in[0];
  const float* ln1_g  = (const float*)d_in[1];
  const float* ln1_b  = (const float*)d_in[2];
  const float* qkv_w  = (const float*)d_in[3];
  const float* qkv_b  = (const float*)d_in[4];
  const float* proj_w = (const float*)d_in[5];
  const float* proj_b = (const float*)d_in[6];
  const float* ln2_g  = (const float*)d_in[7];
  const float* ln2_b  = (const float*)d_in[8];
  const float* ff1_w  = (const float*)d_in[9];
  const float* ff1_b  = (const float*)d_in[10];
  const float* ff2_w  = (const float*)d_in[11];
  const float* ff2_b  = (const float*)d_in[12];
  float* out = (float*)d_out;

  char* ws = (char*)d_ws;
  size_t off = 0;
  unsigned short* wbuf   = (unsigned short*)(ws + off); off += (size_t)4096 * 1024 * 2;  // 8 MiB
  unsigned short* hbuf   = (unsigned short*)(ws + off); off += (size_t)8192 * 1024 * 2;  // 16 MiB
  unsigned short* qkvbuf = (unsigned short*)(ws + off); off += (size_t)8192 * 3072 * 2;  // 48 MiB
  unsigned short* gbuf   = (unsigned short*)(ws + off);                                   // 64 MiB

  // ---- attention sublayer ----
  ln_kernel<<<8192, 256, 0, stream>>>(x, ln1_g, ln1_b, hbuf);
  transpose_kernel<<<dim3(3072 / 64, 1024 / 64), 256, 0, stream>>>(qkv_w, wbuf, 1024, 3072);
  gemm8_kernel<0><<<dim3(64 * 12), 512, 0, stream>>>(hbuf, wbuf, qkv_b, nullptr, qkvbuf,
                                                     8192, 3072, 1024);
  attn_kernel<<<dim3(16, 64), 256, 0, stream>>>(qkvbuf, hbuf);
  transpose_kernel<<<dim3(1024 / 64, 1024 / 64), 256, 0, stream>>>(proj_w, wbuf, 1024, 1024);
  gemm8_kernel<1><<<dim3(64 * 4), 512, 0, stream>>>(hbuf, wbuf, proj_b, x, out,
                                                    8192, 1024, 1024);   // x1 -> d_out (f32)
  // ---- MLP sublayer ----
  ln_kernel<<<8192, 256, 0, stream>>>(out, ln2_g, ln2_b, hbuf);
  transpose_kernel<<<dim3(4096 / 64, 1024 / 64), 256, 0, stream>>>(ff1_w, wbuf, 1024, 4096);
  gemm8_kernel<2><<<dim3(64 * 16), 512, 0, stream>>>(hbuf, wbuf, ff1_b, nullptr, gbuf,
                                                     8192, 4096, 1024);  // gelu
  transpose_kernel<<<dim3(1024 / 64, 4096 / 64), 256, 0, stream>>>(ff2_w, wbuf, 4096, 1024);
  gemm8_kernel<1><<<dim3(64 * 4), 512, 0, stream>>>(gbuf, wbuf, ff2_b, out, out,
                                                    8192, 1024, 4096);   // + x1 in-place
}

// Round 8
// 440.852 us; speedup vs baseline: 1.0982x; 1.0982x over previous
//
#include <hip/hip_runtime.h>

typedef __attribute__((ext_vector_type(4))) float f32x4;
typedef __attribute__((ext_vector_type(8))) short s16x8;
typedef __attribute__((ext_vector_type(4))) unsigned short u16x4;

#define DEV __device__ __forceinline__

DEV unsigned short f2bf(float f) {
  unsigned int u = __float_as_uint(f);
  return (unsigned short)((u + 0x7FFFu + ((u >> 16) & 1u)) >> 16);
}

DEV float exp2_asm(float x) {        // v_exp_f32: D = 2^S0
  float r; asm("v_exp_f32 %0, %1" : "=v"(r) : "v"(x)); return r;
}
DEV float rcp_asm(float x) {
  float r; asm("v_rcp_f32 %0, %1" : "=v"(r) : "v"(x)); return r;
}

DEV void gload_lds16(const void* g, void* l) {
  __builtin_amdgcn_global_load_lds(
      (const __attribute__((address_space(1))) unsigned int*)g,
      (__attribute__((address_space(3))) unsigned int*)l, 16, 0, 0);
}

// ---------------- LayerNorm: fp32 in -> bf16 out (rows of 1024) ----------------
__global__ __launch_bounds__(256) void ln_kernel(
    const float* __restrict__ x, const float* __restrict__ gam,
    const float* __restrict__ bet, unsigned short* __restrict__ o)
{
  const int row = blockIdx.x;
  const int tid = threadIdx.x;
  f32x4 v = *(const f32x4*)(x + (size_t)row * 1024 + tid * 4);
  float s = v[0] + v[1] + v[2] + v[3];
  float s2 = v[0]*v[0] + v[1]*v[1] + v[2]*v[2] + v[3]*v[3];
  #pragma unroll
  for (int m = 1; m < 64; m <<= 1) { s += __shfl_xor(s, m); s2 += __shfl_xor(s2, m); }
  __shared__ float ps[4], ps2[4];
  const int wid = tid >> 6, lane = tid & 63;
  if (lane == 0) { ps[wid] = s; ps2[wid] = s2; }
  __syncthreads();
  s = ps[0] + ps[1] + ps[2] + ps[3];
  s2 = ps2[0] + ps2[1] + ps2[2] + ps2[3];
  const float mu = s * (1.0f / 1024.0f);
  const float rstd = rsqrtf(s2 * (1.0f / 1024.0f) - mu * mu + 1e-5f);
  f32x4 g4 = *(const f32x4*)(gam + tid * 4);
  f32x4 b4 = *(const f32x4*)(bet + tid * 4);
  u16x4 ov;
  #pragma unroll
  for (int j = 0; j < 4; j++) ov[j] = f2bf((v[j] - mu) * rstd * g4[j] + b4[j]);
  *(u16x4*)(o + (size_t)row * 1024 + tid * 4) = ov;
}

// -------- transpose+convert: W[K][N] f32 -> WT[N][K] bf16 (64x64 LDS tiles) --------
__global__ __launch_bounds__(256) void transpose_kernel(
    const float* __restrict__ W, unsigned short* __restrict__ WT, int K, int N)
{
  __shared__ float tile[64][65];
  const int n0 = blockIdx.x * 64, k0 = blockIdx.y * 64;
  const int c = threadIdx.x & 63, r0 = threadIdx.x >> 6;
  #pragma unroll
  for (int r = r0; r < 64; r += 4)
    tile[r][c] = W[(size_t)(k0 + r) * N + n0 + c];
  __syncthreads();
  #pragma unroll
  for (int r = r0; r < 64; r += 4)
    WT[(size_t)(n0 + r) * K + k0 + c] = f2bf(tile[c][r]);
}

// --- 128x256 GEMM, BK=64, XOR-swizzled LDS, 3-slot ring, ONE barrier/K-tile ---
// MODE 0: out bf16, cols<1024 pre-scaled by 0.125*log2e (Q for attn);
// MODE 1: out f32 = v + resid; MODE 2: out bf16 = gelu(v)
template <int MODE>
__global__ __launch_bounds__(512) void gemm8_kernel(
    const unsigned short* __restrict__ A, const unsigned short* __restrict__ WT,
    const float* __restrict__ bias, const float* resid, void* outp,
    int M, int N, int K)
{
  __shared__ unsigned short lds[3 * 24576];   // slot: A 128x64 (16KB) + B 256x64 (32KB)
  const int tid = threadIdx.x;
  const int lane = tid & 63, wid = tid >> 6;
  const int l15 = lane & 15, l4 = lane >> 4;
  const int wm = wid >> 2, wn = wid & 3;
  const int tiles_n = N >> 8;
  const int cpx = gridDim.x >> 3;
  const int id = (blockIdx.x & 7) * cpx + (blockIdx.x >> 3);
  const int bm = id / tiles_n, bn = id % tiles_n;
  const int NT = K >> 6;

  const int srow = tid >> 3;
  const int scol = ((tid & 7) ^ (srow & 7)) * 8;
  const unsigned short* Asrc = A  + (size_t)(bm * 128 + srow) * K + scol;
  const unsigned short* Bsrc = WT + (size_t)(bn * 256 + srow) * K + scol;
  const size_t j64 = (size_t)64 * K;
  const int dwave = wid * 1024;

#define STAGE(t_, ss_) do { \
    char* base_ = (char*)lds + (ss_) * 49152 + dwave; \
    const unsigned short* sA_ = Asrc + (size_t)(t_) * 64; \
    const unsigned short* sB_ = Bsrc + (size_t)(t_) * 64; \
    gload_lds16(sA_,            base_); \
    gload_lds16(sA_ + j64,      base_ + 8192); \
    gload_lds16(sB_,            base_ + 16384); \
    gload_lds16(sB_ + j64,      base_ + 16384 + 8192); \
    gload_lds16(sB_ + 2 * j64,  base_ + 16384 + 16384); \
    gload_lds16(sB_ + 3 * j64,  base_ + 16384 + 24576); \
  } while (0)

  f32x4 acc[4][4] = {};

  const int arow0 = wm * 64 + l15;
  const int brow0 = wn * 64 + l15;
  const int cswz = l15 & 7;

  STAGE(0, 0);
  STAGE(1, 1);
  asm volatile("s_waitcnt vmcnt(6)" ::: "memory");
  __builtin_amdgcn_s_barrier();

  int cs = 0, ss = 2;
  for (int t = 0; t < NT; ++t) {
    const unsigned short* sa = lds + cs * 24576;
    const unsigned short* sb = sa + 8192;
    s16x8 af[4][2], bf[4][2];
    #pragma unroll
    for (int mf = 0; mf < 4; ++mf)
      #pragma unroll
      for (int ks = 0; ks < 2; ++ks)
        af[mf][ks] = *(const s16x8*)&sa[(arow0 + mf * 16) * 64 + (((ks * 4 + l4) ^ cswz) * 8)];
    #pragma unroll
    for (int nf = 0; nf < 4; ++nf)
      #pragma unroll
      for (int ks = 0; ks < 2; ++ks)
        bf[nf][ks] = *(const s16x8*)&sb[(brow0 + nf * 16) * 64 + (((ks * 4 + l4) ^ cswz) * 8)];
    if (t + 2 < NT) STAGE(t + 2, ss);
    __builtin_amdgcn_s_setprio(1);
    #pragma unroll
    for (int mf = 0; mf < 4; ++mf)
      #pragma unroll
      for (int nf = 0; nf < 4; ++nf)
        #pragma unroll
        for (int ks = 0; ks < 2; ++ks)
          acc[mf][nf] = __builtin_amdgcn_mfma_f32_16x16x32_bf16(
              af[mf][ks], bf[nf][ks], acc[mf][nf], 0, 0, 0);
    __builtin_amdgcn_s_setprio(0);
    if (t + 2 < NT)      { asm volatile("s_waitcnt vmcnt(6)" ::: "memory"); }
    else if (t + 1 < NT) { asm volatile("s_waitcnt vmcnt(0)" ::: "memory"); }
    __builtin_amdgcn_s_barrier();
    cs = (cs == 2) ? 0 : cs + 1;
    ss = (ss == 2) ? 0 : ss + 1;
  }
#undef STAGE

  #pragma unroll
  for (int nf = 0; nf < 4; nf++) {
    const int col = bn * 256 + wn * 64 + nf * 16 + l15;
    const float bv = bias[col];
    const float qs = (MODE == 0 && col < 1024) ? 0.18033688f : 1.0f;  // Q pre-scale
    #pragma unroll
    for (int mf = 0; mf < 4; mf++) {
      #pragma unroll
      for (int r = 0; r < 4; r++) {
        const int row = bm * 128 + wm * 64 + mf * 16 + l4 * 4 + r;
        const size_t off = (size_t)row * N + col;
        float v = acc[mf][nf][r] + bv;
        if (MODE == 1) {
          ((float*)outp)[off] = v + resid[off];
        } else if (MODE == 2) {
          const float u = v + 0.044715f * v * v * v;
          const float e = exp2_asm(-2.3022010f * u);
          ((unsigned short*)outp)[off] = f2bf(v * rcp_asm(1.0f + e));
        } else {
          ((unsigned short*)outp)[off] = f2bf(v * qs);
        }
      }
    }
  }
}

// ---------------- causal flash attention ----------------
// R8 = R6 structure (separate qA/qB tile passes, R6 swizzles, async K/V
// prefetch, counted vmcnt) + VALU cuts: Q pre-scaled upstream (no per-elem
// scale mul), wave-uniform mask branch (mask only on diagonal tiles),
// truncating bf16 pack for P.
struct AttnState {
  f32x4 o[4];
  float m, l;
};

DEV void attn_tile(const s16x8* qf, const unsigned short* Ks,
                   const unsigned short* Vt, unsigned short* Pw,
                   AttnState& st, int kv0, int qg, int l15, int l4, bool need_mask)
{
  f32x4 sa[4];
  #pragma unroll
  for (int cb = 0; cb < 4; cb++) sa[cb] = (f32x4){0.f, 0.f, 0.f, 0.f};
  __builtin_amdgcn_s_setprio(1);
  #pragma unroll
  for (int ks = 0; ks < 2; ++ks) {
    #pragma unroll
    for (int cb = 0; cb < 4; cb++) {
      const int kvr = cb * 16 + l15;
      s16x8 bk = *(const s16x8*)&Ks[kvr * 64 + ((ks * 32 + l4 * 8) ^ ((kvr & 7) << 3))];
      sa[cb] = __builtin_amdgcn_mfma_f32_16x16x32_bf16(bk, qf[ks], sa[cb], 0, 0, 0);
    }
  }
  __builtin_amdgcn_s_setprio(0);
  // S already in log2 units (Q pre-scaled by 0.125*log2e in GEMM epilogue)
  if (need_mask) {                               // wave-uniform: diagonal tiles only
    const int thr = qg - kv0 - l4 * 4;
    #pragma unroll
    for (int cb = 0; cb < 4; cb++)
      #pragma unroll
      for (int r = 0; r < 4; r++)
        if (cb * 16 + r > thr) sa[cb][r] = -3.0e38f;
  }
  float mcb[4];
  #pragma unroll
  for (int cb = 0; cb < 4; cb++)
    mcb[cb] = fmaxf(fmaxf(sa[cb][0], sa[cb][1]), fmaxf(sa[cb][2], sa[cb][3]));
  float mx = fmaxf(fmaxf(mcb[0], mcb[1]), fmaxf(mcb[2], mcb[3]));
  mx = fmaxf(mx, __shfl_xor(mx, 16));
  mx = fmaxf(mx, __shfl_xor(mx, 32));
  const bool skip = __all(mx <= st.m + 11.5f);   // defer-max: P bounded by 2^11.5
  const float mnew = skip ? st.m : fmaxf(st.m, mx);
  float rsum = 0.f;
  #pragma unroll
  for (int cb = 0; cb < 4; cb++) {
    u16x4 pw;
    #pragma unroll
    for (int r = 0; r < 4; r++) {
      const float p = exp2_asm(sa[cb][r] - mnew);
      rsum += p;
      pw[r] = (unsigned short)(__float_as_uint(p) >> 16);   // truncating bf16
    }
    *(u16x4*)&Pw[l15 * 64 + ((cb * 16 + l4 * 4) ^ ((l15 & 7) << 3))] = pw;
  }
  rsum += __shfl_xor(rsum, 16);
  rsum += __shfl_xor(rsum, 32);
  if (skip) {
    st.l += rsum;
  } else {
    const float alpha = exp2_asm(st.m - mnew);
    st.l = st.l * alpha + rsum;
    st.m = mnew;
    #pragma unroll
    for (int r = 0; r < 4; r++) {
      const float ar = __shfl(alpha, l4 * 4 + r);
      #pragma unroll
      for (int cb = 0; cb < 4; cb++) st.o[cb][r] *= ar;
    }
  }
  asm volatile("s_waitcnt lgkmcnt(0)" ::: "memory");  // P writes visible to own wave
  __builtin_amdgcn_s_setprio(1);
  #pragma unroll
  for (int ks = 0; ks < 2; ++ks) {
    s16x8 pa = *(const s16x8*)&Pw[l15 * 64 + ((ks * 32 + l4 * 8) ^ ((l15 & 7) << 3))];
    #pragma unroll
    for (int cb = 0; cb < 4; cb++) {
      const int d = cb * 16 + l15;
      s16x8 vf = *(const s16x8*)&Vt[d * 64 + ((ks * 32 + l4 * 8) ^ (((d >> 2) & 7) << 3))];
      st.o[cb] = __builtin_amdgcn_mfma_f32_16x16x32_bf16(pa, vf, st.o[cb], 0, 0, 0);
    }
  }
  __builtin_amdgcn_s_setprio(0);
}

DEV void attn_write(unsigned short* orow, const AttnState& st, int l15, int l4) {
  const float invl = rcp_asm(st.l);
  #pragma unroll
  for (int r = 0; r < 4; r++) {
    const float ir = __shfl(invl, l4 * 4 + r);
    #pragma unroll
    for (int cb = 0; cb < 4; cb++)
      orow[(l4 * 4 + r) * 1024 + cb * 16 + l15] = f2bf(st.o[cb][r] * ir);
  }
}

__global__ __launch_bounds__(256) void attn_kernel(
    const unsigned short* __restrict__ qkv, unsigned short* __restrict__ outb)
{
  __shared__ unsigned short Ks[2][64 * 64];       // [kv][d^((kv&7)<<3)], double-buffered
  __shared__ unsigned short Vt[64 * 64];          // [d][kv^(((d>>2)&7)<<3)]
  __shared__ unsigned short Ps[2][4][16 * 64];    // per-q-tile, per-wave P
  const int pid = blockIdx.x;                     // 0..15
  const int qA = pid, qB = 31 - pid;
  const int bh = blockIdx.y;
  const int b = bh >> 4, h = bh & 15;
  const int tid = threadIdx.x, lane = tid & 63, wid = tid >> 6;
  const int l15 = lane & 15, l4 = lane >> 4;
  const size_t base = (size_t)b * 2048 * 3072 + (size_t)h * 64;
  const unsigned short* Qb = qkv + base;
  const unsigned short* Kb = qkv + base + 1024;
  const unsigned short* Vb = qkv + base + 2048;

  s16x8 qfA[2], qfB[2];
  {
    const unsigned short* qr = Qb + (size_t)(qA * 64 + wid * 16 + l15) * 3072 + l4 * 8;
    qfA[0] = *(const s16x8*)qr;
    qfA[1] = *(const s16x8*)(qr + 32);
    qr = Qb + (size_t)(qB * 64 + wid * 16 + l15) * 3072 + l4 * 8;
    qfB[0] = *(const s16x8*)qr;
    qfB[1] = *(const s16x8*)(qr + 32);
  }

  // prologue: V(0) reg loads FIRST, then K(0) gload_lds (vmcnt counts rely on order)
  u16x4 vv[4];
  #pragma unroll
  for (int it = 0; it < 4; ++it) {
    const int cc = tid + 256 * it;
    vv[it] = *(const u16x4*)(Vb + (size_t)(cc >> 4) * 3072 + (cc & 15) * 4);
  }
  #pragma unroll
  for (int s = 0; s < 2; ++s) {
    const int c = s * 256 + tid;
    const int kv = c >> 3;
    const int dsrc = ((c & 7) * 8) ^ ((kv & 7) << 3);
    gload_lds16(Kb + (size_t)kv * 3072 + dsrc, &Ks[0][(size_t)(c & ~63) * 8]);
  }

  AttnState sA, sB;
  #pragma unroll
  for (int cb = 0; cb < 4; cb++) {
    sA.o[cb] = (f32x4){0.f, 0.f, 0.f, 0.f};
    sB.o[cb] = (f32x4){0.f, 0.f, 0.f, 0.f};
  }
  sA.m = -1e30f; sA.l = 0.f; sB.m = -1e30f; sB.l = 0.f;
  const int qgA = qA * 64 + wid * 16 + l15;
  const int qgB = qB * 64 + wid * 16 + l15;

  for (int kvb = 0; kvb <= qB; ++kvb) {
    const int cur = kvb & 1;
    const int kv0 = kvb * 64;
    __builtin_amdgcn_s_barrier();                 // #1: prev tile fully consumed
    asm volatile("s_waitcnt vmcnt(2)" ::: "memory");   // V(kvb) regs landed; K(kvb) flying
    #pragma unroll
    for (int it = 0; it < 4; ++it) {
      const int cc = tid + 256 * it;
      const int vkv = cc >> 4;
      const int vd = (cc & 15) * 4;
      #pragma unroll
      for (int j = 0; j < 4; j++) {
        const int d = vd + j;
        Vt[d * 64 + (vkv ^ (((d >> 2) & 7) << 3))] = vv[it][j];
      }
    }
    if (kvb < qB) {
      #pragma unroll
      for (int it = 0; it < 4; ++it) {
        const int cc = tid + 256 * it;
        vv[it] = *(const u16x4*)(Vb + (size_t)((kvb + 1) * 64 + (cc >> 4)) * 3072 + (cc & 15) * 4);
      }
      asm volatile("s_waitcnt vmcnt(4)" ::: "memory");  // K(kvb) landed; V(kvb+1) flying
    } else {
      asm volatile("s_waitcnt vmcnt(0)" ::: "memory");
    }
    asm volatile("s_waitcnt lgkmcnt(0)" ::: "memory");  // Vt ds_writes drained
    __builtin_amdgcn_s_barrier();                 // #2: Ks[cur], Vt published
    if (kvb < qB) {
      #pragma unroll
      for (int s = 0; s < 2; ++s) {
        const int c = s * 256 + tid;
        const int kv = c >> 3;
        const int dsrc = ((c & 7) * 8) ^ ((kv & 7) << 3);
        gload_lds16(Kb + (size_t)((kvb + 1) * 64 + kv) * 3072 + dsrc,
                    &Ks[cur ^ 1][(size_t)(c & ~63) * 8]);
      }
    }
    if (kvb <= qA)
      attn_tile(qfA, Ks[cur], Vt, Ps[0][wid], sA, kv0, qgA, l15, l4,
                kv0 + 63 > qA * 64 + wid * 16);
    attn_tile(qfB, Ks[cur], Vt, Ps[1][wid], sB, kv0, qgB, l15, l4,
              kv0 + 63 > qB * 64 + wid * 16);
  }
  attn_write(outb + ((size_t)b * 2048 + qA * 64 + wid * 16) * 1024 + h * 64, sA, l15, l4);
  attn_write(outb + ((size_t)b * 2048 + qB * 64 + wid * 16) * 1024 + h * 64, sB, l15, l4);
}

// ---------------- host ----------------
extern "C" void kernel_launch(void* const* d_in, const int* in_sizes, int n_in,
                              void* d_out, int out_size, void* d_ws, size_t ws_size,
                              hipStream_t stream) {
  const float* x      = (const float*)d_in[0];
  const float* ln1_g  = (const float*)d_in[1];
  const float* ln1_b  = (const float*)d_in[2];
  const float* qkv_w  = (const float*)d_in[3];
  const float* qkv_b  = (const float*)d_in[4];
  const float* proj_w = (const float*)d_in[5];
  const float* proj_b = (const float*)d_in[6];
  const float* ln2_g  = (const float*)d_in[7];
  const float* ln2_b  = (const float*)d_in[8];
  const float* ff1_w  = (const float*)d_in[9];
  const float* ff1_b  = (const float*)d_in[10];
  const float* ff2_w  = (const float*)d_in[11];
  const float* ff2_b  = (const float*)d_in[12];
  float* out = (float*)d_out;

  char* ws = (char*)d_ws;
  size_t off = 0;
  unsigned short* wbuf   = (unsigned short*)(ws + off); off += (size_t)4096 * 1024 * 2;  // 8 MiB
  unsigned short* hbuf   = (unsigned short*)(ws + off); off += (size_t)8192 * 1024 * 2;  // 16 MiB
  unsigned short* qkvbuf = (unsigned short*)(ws + off); off += (size_t)8192 * 3072 * 2;  // 48 MiB
  unsigned short* gbuf   = (unsigned short*)(ws + off);                                   // 64 MiB

  // ---- attention sublayer ----
  ln_kernel<<<8192, 256, 0, stream>>>(x, ln1_g, ln1_b, hbuf);
  transpose_kernel<<<dim3(3072 / 64, 1024 / 64), 256, 0, stream>>>(qkv_w, wbuf, 1024, 3072);
  gemm8_kernel<0><<<dim3(64 * 12), 512, 0, stream>>>(hbuf, wbuf, qkv_b, nullptr, qkvbuf,
                                                     8192, 3072, 1024);
  attn_kernel<<<dim3(16, 64), 256, 0, stream>>>(qkvbuf, hbuf);
  transpose_kernel<<<dim3(1024 / 64, 1024 / 64), 256, 0, stream>>>(proj_w, wbuf, 1024, 1024);
  gemm8_kernel<1><<<dim3(64 * 4), 512, 0, stream>>>(hbuf, wbuf, proj_b, x, out,
                                                    8192, 1024, 1024);   // x1 -> d_out (f32)
  // ---- MLP sublayer ----
  ln_kernel<<<8192, 256, 0, stream>>>(out, ln2_g, ln2_b, hbuf);
  transpose_kernel<<<dim3(4096 / 64, 1024 / 64), 256, 0, stream>>>(ff1_w, wbuf, 1024, 4096);
  gemm8_kernel<2><<<dim3(64 * 16), 512, 0, stream>>>(hbuf, wbuf, ff1_b, nullptr, gbuf,
                                                     8192, 4096, 1024);  // gelu
  transpose_kernel<<<dim3(1024 / 64, 4096 / 64), 256, 0, stream>>>(ff2_w, wbuf, 4096, 1024);
  gemm8_kernel<1><<<dim3(64 * 4), 512, 0, stream>>>(gbuf, wbuf, ff2_b, out, out,
                                                    8192, 1024, 4096);   // + x1 in-place
}